// Round 14
// baseline (2134.951 us; speedup 1.0000x reference)
//
#include <hip/hip_runtime.h>
#include <hip/hip_bf16.h>

constexpr int Nn  = 32768;   // total nodes
constexpr int Ej  = 294912;  // total edges
constexpr int Bg  = 256;     // graphs
constexpr int EPG = 1152;    // edges per graph
constexpr int WC  = 208;     // fused-GEMM cols per head: q64|k64|v64|r8:8|qb1|pad
constexpr int ASF = 304;     // abuf row floats: agg[0,256) | t8[256,288) | s[288,292) | pad

// ---- k_attn LDS offset map (bytes), total 81152 <= 81920 (2 blocks/CU) ----
// [0,18432)      hB bf16[128][72]   P-1..P0b   -> part of S      -> vL bf16[128][72] (P3..P4)
// [18432,36864)  WT bf16 (qk 128 rows, then v 80 rows)  P-1..P0b -> part of S
//                S bf16[128][132] spans [0,33792)  P1..P2b
// [33792,34304)  qbL f32[128]       P2a..P2b
// [34304,34816)  mL  u32[128]       P2a..P3
// [34816,35328)  sL  f32[128]       P2a..P5wb
// [36864,55296)  Qu bf16[128][72]   P0a..P1  -> r8L f32[128][8] (P2a..P2b) -> aggv head
// [55296,73728)  Ku bf16[128][72]   P0a..P1  -> aggv f32[128][64] spans [36864,69632)
// [69632,74240)  t8L f32[128][9]    zero P2a, accum P3, read P5wb
// [74240,78848)  alphaL f32[1152]   P2b..P4
// [78848,81152)  edL u16[1152]      P-1..P4
constexpr int O_HB = 0, O_WT = 18432, O_QB = 33792, O_ML = 34304, O_SL = 34816;
constexpr int O_QU = 36864, O_KU = 55296, O_T8 = 69632, O_AL = 74240, O_ED = 78848;
constexpr int LDS_SZ = 81152;

typedef __attribute__((ext_vector_type(8))) short short8;   // 8 bf16 (MFMA A/B frag)
typedef __attribute__((ext_vector_type(4))) float f32x4;    // MFMA C/D frag

__device__ __forceinline__ unsigned encf(float f) {
  unsigned u = __float_as_uint(f);
  return (u & 0x80000000u) ? ~u : (u | 0x80000000u);
}
__device__ __forceinline__ float decf(unsigned u) {
  return (u & 0x80000000u) ? __uint_as_float(u & 0x7FFFFFFFu) : __uint_as_float(~u);
}
__device__ __forceinline__ unsigned short f2bf(float f) {
  unsigned u = __float_as_uint(f);
  u += 0x7FFFu + ((u >> 16) & 1u);
  return (unsigned short)(u >> 16);
}
__device__ __forceinline__ float bf2f(unsigned short u) {
  return __uint_as_float(((unsigned)u) << 16);
}
__device__ __forceinline__ float wave_red_sum(float x) {
  x += __int_as_float(__builtin_amdgcn_update_dpp(0, __float_as_int(x), 0x111, 0xf, 0xf, true));
  x += __int_as_float(__builtin_amdgcn_update_dpp(0, __float_as_int(x), 0x112, 0xf, 0xf, true));
  x += __int_as_float(__builtin_amdgcn_update_dpp(0, __float_as_int(x), 0x114, 0xf, 0xf, true));
  x += __int_as_float(__builtin_amdgcn_update_dpp(0, __float_as_int(x), 0x118, 0xf, 0xf, true));
  x += __int_as_float(__builtin_amdgcn_update_dpp(0, __float_as_int(x), 0x142, 0xf, 0xf, true));
  x += __int_as_float(__builtin_amdgcn_update_dpp(0, __float_as_int(x), 0x143, 0xf, 0xf, true));
  return x;
}

// h[n,c] = sum_d x[n,d] * Wn[d,c] + bn[c]   (XD=16)
__global__ void k_node_enc(const float* __restrict__ x, const float* __restrict__ W,
                           const float* __restrict__ b, float* __restrict__ h) {
  int tid = blockIdx.x * 256 + threadIdx.x;  // Nn*64
  int n = tid >> 6, c = tid & 63;
  float acc = b[c];
#pragma unroll
  for (int d = 0; d < 16; ++d)
    acc += x[n * 16 + d] * W[d * 64 + c];
  h[tid] = acc;
}

// G[l][h][a][c] = sum_d W_edge[a,d]*We_l[d][h64+c];  bb[l][h][c] = be + b_edge@We
__global__ void k_prep2(const float* __restrict__ We, const float* __restrict__ be,
                        const float* __restrict__ W_edge, const float* __restrict__ b_edge,
                        float* __restrict__ G, float* __restrict__ bb) {
  int tid = blockIdx.x * 256 + threadIdx.x;  // 8192 + 1024
  if (tid < 8192) {
    int l = tid >> 11, rem = tid & 2047;
    int hh = rem >> 9, a = (rem >> 6) & 7, c = rem & 63;
    float acc = 0.f;
#pragma unroll 8
    for (int d = 0; d < 64; ++d)
      acc += W_edge[a * 64 + d] * We[l * 16384 + d * 256 + hh * 64 + c];
    G[tid] = acc;
  } else if (tid < 9216) {
    int t = tid - 8192;
    int l = t >> 8, rem = t & 255;
    int hh = rem >> 6, c = rem & 63;
    float acc = be[l * 256 + hh * 64 + c];
#pragma unroll 8
    for (int d = 0; d < 64; ++d)
      acc += b_edge[d] * We[l * 16384 + d * 256 + hh * 64 + c];
    bb[t] = acc;
  }
}

// Light cols of WcatT (bf16, [l][h][col][k]) + bcatT (fp32). Reads d_in only.
__global__ void k_prepT_light(const float* __restrict__ Wq, const float* __restrict__ bq,
                              const float* __restrict__ Wk, const float* __restrict__ bk,
                              const float* __restrict__ Wv, const float* __restrict__ bv,
                              unsigned short* __restrict__ WcatT, float* __restrict__ bcatT) {
  int tid = blockIdx.x * 256 + threadIdx.x;  // 4*4*WC*64
  if (tid >= 4 * 4 * WC * 64) return;
  int kk = tid & 63;
  int rest = tid >> 6;
  int col = rest % WC;
  int lh = rest / WC;
  int h = lh & 3, l = lh >> 2;
  float w, bias;
  if (col < 64) {
    w = 0.125f * Wq[l * 16384 + kk * 256 + h * 64 + col];
    bias = 0.125f * bq[l * 256 + h * 64 + col];
  } else if (col < 128) {
    int j = col - 64;
    w = Wk[l * 16384 + kk * 256 + h * 64 + j];
    bias = bk[l * 256 + h * 64 + j];
  } else if (col < 192) {
    int j = col - 128;
    w = Wv[l * 16384 + kk * 256 + h * 64 + j];
    bias = bv[l * 256 + h * 64 + j];
  } else if (col < 201) {
    return;  // heavy
  } else {
    w = 0.f; bias = 0.f;
  }
  WcatT[(size_t)(lh * WC + col) * 64 + kk] = f2bf(w);
  if (kk == 0) bcatT[lh * WC + col] = bias;
}

// Heavy cols (r8 at 192..199, qb' at 200): one WAVE per element. Reads d_in only.
__global__ void __launch_bounds__(256) k_prepT_heavy(
    const float* __restrict__ Wq, const float* __restrict__ bq,
    const float* __restrict__ We, const float* __restrict__ be,
    const float* __restrict__ W_edge, const float* __restrict__ b_edge,
    unsigned short* __restrict__ WcatT, float* __restrict__ bcatT) {
  int eid = blockIdx.x * 4 + (threadIdx.x >> 6);  // 2304 blocks * 4 waves
  int lane = threadIdx.x & 63;
  int l = eid / 2304;
  int rem = eid % 2304;
  int kk = rem / 36, j = rem % 36;
  int hh, col;
  float inner;
  const float* We_l = We + l * 16384;
  if (j < 32) {
    hh = j >> 3;
    int a = j & 7;
    col = 192 + a;
    float s = 0.f;
#pragma unroll 8
    for (int d = 0; d < 64; ++d)
      s += We_l[d * 256 + hh * 64 + lane] * W_edge[a * 64 + d];
    inner = s;
  } else {
    hh = j - 32;
    col = 200;
    float s = be[l * 256 + hh * 64 + lane];
#pragma unroll 8
    for (int d = 0; d < 64; ++d)
      s += b_edge[d] * We_l[d * 256 + hh * 64 + lane];
    inner = s;
  }
  float w = Wq[l * 16384 + kk * 256 + hh * 64 + lane] * inner;
  float b2 = bq[l * 256 + hh * 64 + lane] * inner;
  float sw = wave_red_sum(w);
  float sb = wave_red_sum(b2);
  if (lane == 63) {
    int lh = l * 4 + hh;
    WcatT[(size_t)(lh * WC + col) * 64 + kk] = f2bf(0.125f * sw);
    if (kk == 0) bcatT[lh * WC + col] = 0.125f * sb;
  }
}

// Fused QKV-GEMM + attention, 81152 B LDS => 2 blocks/CU. Block=(g,h), 1024 thr.
__global__ void __launch_bounds__(1024, 8) k_attn(const float* __restrict__ hbuf,
                                                  const unsigned short* __restrict__ WcatT_l,
                                                  const float* __restrict__ bcatT_l,
                                                  float* __restrict__ abuf,
                                                  const float* __restrict__ edge_attr,
                                                  const int* __restrict__ ei) {
  __shared__ char smem[LDS_SZ];
  unsigned short* hB = (unsigned short*)(smem + O_HB);   // stride 72
  unsigned short* WT = (unsigned short*)(smem + O_WT);   // stride 72
  unsigned short* Su = (unsigned short*)(smem + O_HB);   // S bf16 stride 132
  unsigned short* vL = (unsigned short*)(smem + O_HB);   // stride 72 (P3+)
  unsigned short* Qu = (unsigned short*)(smem + O_QU);   // stride 72
  unsigned short* Ku = (unsigned short*)(smem + O_KU);   // stride 72
  float* qbL = (float*)(smem + O_QB);
  unsigned* mL = (unsigned*)(smem + O_ML);
  float* sL = (float*)(smem + O_SL);
  float* r8L = (float*)(smem + O_QU);                    // [128][8] (P2a..P2b)
  float* aggv = (float*)(smem + O_QU);                   // [128][64] (P3+)
  float* t8L = (float*)(smem + O_T8);                    // [128][9]
  float* alphaL = (float*)(smem + O_AL);
  unsigned short* edL = (unsigned short*)(smem + O_ED);

  int g = blockIdx.x, h = blockIdx.y;
  int tid = threadIdx.x;
  int lane = tid & 63, m16 = lane & 15, quad = lane >> 4, wv = tid >> 6;
  int n8 = tid >> 3, c8 = tid & 7;
  const unsigned short* WTg = WcatT_l + (size_t)h * WC * 64;
  const float* bcTl = bcatT_l + (size_t)h * WC;
  float* aF = abuf + (size_t)g * 128 * ASF;
  const float* eaG = edge_attr + (size_t)g * EPG * 8;

  // ---- P-1: stage hB (fp32->bf16), WT_qk rows 0..127, edge list
  {
    const float* hr = hbuf + (size_t)g * 8192 + n8 * 64 + c8 * 8;
    float4 a0 = *(const float4*)(hr), a1 = *(const float4*)(hr + 4);
    uint4 hp;
    hp.x = f2bf(a0.x) | ((unsigned)f2bf(a0.y) << 16);
    hp.y = f2bf(a0.z) | ((unsigned)f2bf(a0.w) << 16);
    hp.z = f2bf(a1.x) | ((unsigned)f2bf(a1.y) << 16);
    hp.w = f2bf(a1.z) | ((unsigned)f2bf(a1.w) << 16);
    *(uint4*)&hB[n8 * 72 + c8 * 8] = hp;
    *(uint4*)&WT[n8 * 72 + c8 * 8] = *(const uint4*)&WTg[(size_t)n8 * 64 + c8 * 8];
  }
  for (int idx = tid; idx < EPG; idx += 1024) {
    int s_ = ei[g * EPG + idx] - g * 128;
    int d_ = ei[Ej + g * EPG + idx] - g * 128;
    edL[idx] = (unsigned short)(s_ | (d_ << 8));
  }
  __syncthreads();

  // ---- P0a: GEMM Q,K (cols 0..127): 64 tiles, 4 per wave
  for (int t = wv; t < 64; t += 16) {
    int m0 = (t & 7) * 16, n0 = (t >> 3) * 16;
    const short8 a0 = *(const short8*)&hB[(m0 + m16) * 72 + quad * 8];
    const short8 a1 = *(const short8*)&hB[(m0 + m16) * 72 + 32 + quad * 8];
    const short8 b0 = *(const short8*)&WT[(n0 + m16) * 72 + quad * 8];
    const short8 b1 = *(const short8*)&WT[(n0 + m16) * 72 + 32 + quad * 8];
    float bias = bcTl[n0 + m16];
    f32x4 acc = {bias, bias, bias, bias};
    acc = __builtin_amdgcn_mfma_f32_16x16x32_bf16(a0, b0, acc, 0, 0, 0);
    acc = __builtin_amdgcn_mfma_f32_16x16x32_bf16(a1, b1, acc, 0, 0, 0);
    if (n0 < 64) {
#pragma unroll
      for (int r = 0; r < 4; ++r)
        Qu[(m0 + quad * 4 + r) * 72 + n0 + m16] = f2bf(acc[r]);
    } else {
#pragma unroll
      for (int r = 0; r < 4; ++r)
        Ku[(m0 + quad * 4 + r) * 72 + (n0 - 64) + m16] = f2bf(acc[r]);
    }
  }
  __syncthreads();

  // ---- P0s: stage WT_v rows 0..79 (cols 128..207) into WT slot
  if (tid < 640) {
    int row = tid >> 3, cc = tid & 7;
    *(uint4*)&WT[row * 72 + cc * 8] = *(const uint4*)&WTg[(size_t)(128 + row) * 64 + cc * 8];
  }
  __syncthreads();

  // ---- P0b: GEMM V,r8,qb (40 tiles); results held in registers
  f32x4 vfrag[2];
  int vm[2], vc[2], vcnt = 0;
  f32x4 rfrag;
  int rm = -1;
  for (int t = wv; t < 40; t += 16) {
    int m0 = (t & 7) * 16, nt = t >> 3;
    const short8 a0 = *(const short8*)&hB[(m0 + m16) * 72 + quad * 8];
    const short8 a1 = *(const short8*)&hB[(m0 + m16) * 72 + 32 + quad * 8];
    const short8 b0 = *(const short8*)&WT[(nt * 16 + m16) * 72 + quad * 8];
    const short8 b1 = *(const short8*)&WT[(nt * 16 + m16) * 72 + 32 + quad * 8];
    float bias = bcTl[128 + nt * 16 + m16];
    f32x4 acc = {bias, bias, bias, bias};
    acc = __builtin_amdgcn_mfma_f32_16x16x32_bf16(a0, b0, acc, 0, 0, 0);
    acc = __builtin_amdgcn_mfma_f32_16x16x32_bf16(a1, b1, acc, 0, 0, 0);
    if (nt < 4) {
      vfrag[vcnt] = acc; vm[vcnt] = m0; vc[vcnt] = nt * 16; ++vcnt;
    } else {
      rfrag = acc; rm = m0;
    }
  }
  __syncthreads();

  // ---- P1: S = Q@K^T, stored bf16 (stride 132)
  {
    int strip = wv >> 1, halfw = wv & 1;
    int dst0 = strip * 16;
    const short8 a0 = *(const short8*)&Qu[(dst0 + m16) * 72 + quad * 8];
    const short8 a1 = *(const short8*)&Qu[(dst0 + m16) * 72 + 32 + quad * 8];
#pragma unroll
    for (int t = 0; t < 4; ++t) {
      int src0 = (halfw * 4 + t) * 16;
      const short8 b0 = *(const short8*)&Ku[(src0 + m16) * 72 + quad * 8];
      const short8 b1 = *(const short8*)&Ku[(src0 + m16) * 72 + 32 + quad * 8];
      f32x4 acc = {0.f, 0.f, 0.f, 0.f};
      acc = __builtin_amdgcn_mfma_f32_16x16x32_bf16(a0, b0, acc, 0, 0, 0);
      acc = __builtin_amdgcn_mfma_f32_16x16x32_bf16(a1, b1, acc, 0, 0, 0);
#pragma unroll
      for (int r = 0; r < 4; ++r)
        Su[(dst0 + quad * 4 + r) * 132 + src0 + m16] = f2bf(acc[r]);
    }
  }
  __syncthreads();

  // ---- P2a: deposit r8/qb (into dead Qu region); init mL/sL; zero t8L; zero aggv tail
  if (rm >= 0) {
#pragma unroll
    for (int r = 0; r < 4; ++r) {
      int node = rm + quad * 4 + r;
      if (m16 < 8) r8L[node * 8 + m16] = rfrag[r];
      else if (m16 == 8) qbL[node] = rfrag[r];
    }
  }
  if (tid < 128) { mL[tid] = 0u; sL[tid] = 0.f; }
  for (int idx = tid; idx < 1152; idx += 1024) t8L[idx] = 0.f;
  for (int idx = tid; idx < 1792; idx += 1024)  // aggv f32[1024..8191] (skip r8L overlap)
    *(float4*)&aggv[1024 + idx * 4] = make_float4(0.f, 0.f, 0.f, 0.f);
  __syncthreads();

  // ---- P2b: per-edge alpha; segment max
  for (int e = tid; e < EPG; e += 1024) {
    int ed = edL[e];
    int src = ed & 255, dst = ed >> 8;
    float4 ea0 = *(const float4*)(eaG + (size_t)e * 8);
    float4 ea1 = *(const float4*)(eaG + (size_t)e * 8 + 4);
    float4 r80 = *(const float4*)&r8L[dst * 8];
    float4 r81 = *(const float4*)&r8L[dst * 8 + 4];
    float a = bf2f(Su[dst * 132 + src]) + qbL[dst]
            + ea0.x * r80.x + ea0.y * r80.y + ea0.z * r80.z + ea0.w * r80.w
            + ea1.x * r81.x + ea1.y * r81.y + ea1.z * r81.z + ea1.w * r81.w;
    alphaL[e] = a;
    atomicMax(&mL[dst], encf(a));
  }
  __syncthreads();

  // ---- P3: deposit V regs -> vL (S dead); zero aggv head; exp + s-sum + t8 accumulate
#pragma unroll
  for (int i = 0; i < 2; ++i) {
#pragma unroll
    for (int r = 0; r < 4; ++r)
      vL[(vm[i] + quad * 4 + r) * 72 + vc[i] + m16] = f2bf(vfrag[i][r]);
  }
  aggv[tid] = 0.f;  // first 1024 f32 (old r8L region)
  for (int e = tid; e < EPG; e += 1024) {
    int dst = edL[e] >> 8;
    float ex = expf(alphaL[e] - decf(mL[dst]));
    alphaL[e] = ex;
    atomicAdd(&sL[dst], ex);
    float4 ea0 = *(const float4*)(eaG + (size_t)e * 8);
    float4 ea1 = *(const float4*)(eaG + (size_t)e * 8 + 4);
    float* t8 = &t8L[dst * 9];
    atomicAdd(t8 + 0, ex * ea0.x); atomicAdd(t8 + 1, ex * ea0.y);
    atomicAdd(t8 + 2, ex * ea0.z); atomicAdd(t8 + 3, ex * ea0.w);
    atomicAdd(t8 + 4, ex * ea1.x); atomicAdd(t8 + 5, ex * ea1.y);
    atomicAdd(t8 + 6, ex * ea1.z); atomicAdd(t8 + 7, ex * ea1.w);
  }
  __syncthreads();

  // ---- P4: per-edge aggregation, wave-per-edge, c-per-lane (unnormalized)
#pragma unroll 4
  for (int e = wv * 72; e < (wv + 1) * 72; ++e) {
    int ed = edL[e];
    int src = ed & 255, dst = ed >> 8;
    float ex = alphaL[e];
    float v = bf2f(vL[src * 72 + lane]);
    atomicAdd(&aggv[dst * 64 + lane], ex * v);
  }
  __syncthreads();

  // ---- P5wb: normalize by s and write abuf
  {
    int n = tid >> 3, cc = tid & 7;
    float inv = 1.f / fmaxf(sL[n], 1e-16f);
    float4 g0 = *(float4*)&aggv[n * 64 + cc * 8];
    float4 g1 = *(float4*)&aggv[n * 64 + cc * 8 + 4];
    g0.x *= inv; g0.y *= inv; g0.z *= inv; g0.w *= inv;
    g1.x *= inv; g1.y *= inv; g1.z *= inv; g1.w *= inv;
    *(float4*)(aF + (size_t)n * ASF + h * 64 + cc * 8) = g0;
    *(float4*)(aF + (size_t)n * ASF + h * 64 + cc * 8 + 4) = g1;
  }
  if (tid < 128) {
    float s = sL[tid];
    float inv = 1.f / fmaxf(s, 1e-16f);
    float tmp[8];
#pragma unroll
    for (int j = 0; j < 8; ++j) tmp[j] = t8L[tid * 9 + j] * inv;
    *(float4*)(aF + (size_t)tid * ASF + 256 + h * 8) = make_float4(tmp[0], tmp[1], tmp[2], tmp[3]);
    *(float4*)(aF + (size_t)tid * ASF + 256 + h * 8 + 4) = make_float4(tmp[4], tmp[5], tmp[6], tmp[7]);
    aF[(size_t)tid * ASF + 288 + h] = s;
  }
}

// out[n,c] = 0.25*sum_h( agg + t8@G_h + (s>0)*bb_h ) + h@Wskip+bskip; vemb; h += out
__global__ void __launch_bounds__(256) k_update(float* h, const float* __restrict__ abuf,
                                                const float* __restrict__ Wskip_l,
                                                const float* __restrict__ bskip_l,
                                                const float* __restrict__ G_l,
                                                const float* __restrict__ bb_l,
                                                float* __restrict__ vemb, int layer) {
  __shared__ float h4[256];
  int n0 = blockIdx.x * 4;
  h4[threadIdx.x] = h[(size_t)n0 * 64 + threadIdx.x];
  __syncthreads();
  int nn = threadIdx.x >> 6, c = threadIdx.x & 63;
  int n = n0 + nn;
  const float* hr = &h4[nn * 64];
  float sk = bskip_l[c];
#pragma unroll 8
  for (int d = 0; d < 64; ++d)
    sk += hr[d] * Wskip_l[d * 64 + c];
  const float* rowA = abuf + (size_t)n * ASF;
  float acc = 0.f;
#pragma unroll
  for (int hh = 0; hh < 4; ++hh) {
    float sw = (rowA[288 + hh] > 0.f) ? 1.f : 0.f;
    float a = rowA[hh * 64 + c] + sw * bb_l[hh * 64 + c];
#pragma unroll
    for (int a8 = 0; a8 < 8; ++a8)
      a += rowA[256 + hh * 8 + a8] * G_l[(hh * 8 + a8) * 64 + c];
    acc += a;
  }
  float outv = acc * 0.25f + sk;
  if ((n & 127) == 127)
    vemb[(n >> 7) * 256 + layer * 64 + c] = outv;
  h[(size_t)n * 64 + c] = outv + hr[c];
}

// pool = vemb @ W_down + b_down; out = sigmoid(pool @ W_out + b_out)
__global__ void k_head(const float* __restrict__ vemb, const float* __restrict__ Wd,
                       const float* __restrict__ bd, const float* __restrict__ Wo,
                       const float* __restrict__ bo, float* __restrict__ out) {
  int g = blockIdx.x;
  int c = threadIdx.x;  // 64 threads
  const float* vr = vemb + g * 256;
  float acc = bd[c];
#pragma unroll 16
  for (int j = 0; j < 256; ++j)
    acc += vr[j] * Wd[j * 64 + c];
  float p = acc * Wo[c];
#pragma unroll
  for (int off = 32; off; off >>= 1) p += __shfl_down(p, off);
  if (c == 0) {
    float logit = p + bo[0];
    out[g] = 1.f / (1.f + expf(-logit));
  }
}

extern "C" void kernel_launch(void* const* d_in, const int* in_sizes, int n_in,
                              void* d_out, int out_size, void* d_ws, size_t ws_size,
                              hipStream_t stream) {
  const float* x         = (const float*)d_in[0];
  const float* edge_attr = (const float*)d_in[1];
  const int*   ei        = (const int*)d_in[2];
  const float* W_node = (const float*)d_in[4];
  const float* b_node = (const float*)d_in[5];
  const float* W_edge = (const float*)d_in[6];
  const float* b_edge = (const float*)d_in[7];
  const float* Wq = (const float*)d_in[8];
  const float* bq = (const float*)d_in[9];
  const float* Wk = (const float*)d_in[10];
  const float* bk = (const float*)d_in[11];
  const float* Wv = (const float*)d_in[12];
  const float* bv = (const float*)d_in[13];
  const float* We = (const float*)d_in[14];
  const float* be = (const float*)d_in[15];
  const float* Wskip = (const float*)d_in[16];
  const float* bskip = (const float*)d_in[17];
  const float* W_down = (const float*)d_in[18];
  const float* b_down = (const float*)d_in[19];
  const float* W_out  = (const float*)d_in[20];
  const float* b_out  = (const float*)d_in[21];
  float* out = (float*)d_out;

  // workspace carve: ~49 MB
  float* p = (float*)d_ws;
  float* hbuf  = p; p += (size_t)Nn * 64;        //  8.4 MB
  float* abuf  = p; p += (size_t)Nn * ASF;       // 39.8 MB
  unsigned short* WcatT = (unsigned short*)p; p += (size_t)4 * 4 * WC * 64 / 2;  // bf16
  float* bcatT = p; p += (size_t)4 * 4 * WC;
  float* Gbuf  = p; p += (size_t)4 * 4 * 8 * 64;
  float* bbuf  = p; p += (size_t)4 * 4 * 64;
  float* vemb  = p; p += (size_t)Bg * 256;

  k_prep2<<<36, 256, 0, stream>>>(We, be, W_edge, b_edge, Gbuf, bbuf);
  k_prepT_light<<<(4 * 4 * WC * 64 + 255) / 256, 256, 0, stream>>>(Wq, bq, Wk, bk, Wv, bv,
                                                                   WcatT, bcatT);
  k_prepT_heavy<<<2304, 256, 0, stream>>>(Wq, bq, We, be, W_edge, b_edge, WcatT, bcatT);
  k_node_enc<<<Nn * 64 / 256, 256, 0, stream>>>(x, W_node, b_node, hbuf);

  for (int i = 0; i < 4; ++i) {
    k_attn<<<dim3(Bg, 4), 1024, 0, stream>>>(hbuf, WcatT + (size_t)i * 4 * WC * 64,
                                             bcatT + (size_t)i * 4 * WC, abuf, edge_attr, ei);
    k_update<<<Nn / 4, 256, 0, stream>>>(hbuf, abuf, Wskip + i * 4096, bskip + i * 64,
                                         Gbuf + i * 2048, bbuf + i * 256, vemb, i);
  }
  k_head<<<Bg, 64, 0, stream>>>(vemb, W_down, b_down, W_out, b_out, out);
}